// Round 1
// baseline (197.307 us; speedup 1.0000x reference)
//
#include <hip/hip_runtime.h>

#define ROWS 16   // batch rows processed per block

// 4-input multilinear LUT node via iterated lerp: 15 lerps == exact multilinear interp.
// Bit i of corner index is the i-th input (LSB = x0), matching reference _BITS.
__device__ __forceinline__ float lut4(const float* __restrict__ t,
                                      float x0, float x1, float x2, float x3) {
    float u0 = fmaf(x0, t[1]  - t[0],  t[0]);
    float u1 = fmaf(x0, t[3]  - t[2],  t[2]);
    float u2 = fmaf(x0, t[5]  - t[4],  t[4]);
    float u3 = fmaf(x0, t[7]  - t[6],  t[6]);
    float u4 = fmaf(x0, t[9]  - t[8],  t[8]);
    float u5 = fmaf(x0, t[11] - t[10], t[10]);
    float u6 = fmaf(x0, t[13] - t[12], t[12]);
    float u7 = fmaf(x0, t[15] - t[14], t[14]);
    float v0 = fmaf(x1, u1 - u0, u0);
    float v1 = fmaf(x1, u3 - u2, u2);
    float v2 = fmaf(x1, u5 - u4, u4);
    float v3 = fmaf(x1, u7 - u6, u6);
    float w0 = fmaf(x2, v1 - v0, v0);
    float w1 = fmaf(x2, v3 - v2, v2);
    return fmaf(x3, w1 - w0, w0);
}

__global__ __launch_bounds__(256) void lut_tree_kernel(
    const float* __restrict__ x,
    const float* __restrict__ t0, const float* __restrict__ t1,
    const float* __restrict__ t2, const float* __restrict__ t3,
    const float* __restrict__ t4, float* __restrict__ out) {

    __shared__ float s0[ROWS * 256];
    __shared__ float s1[ROWS * 64];
    __shared__ float s2[ROWS * 16];
    __shared__ float s3[ROWS * 4];

    const int tid = threadIdx.x;
    const int rowBase = blockIdx.x * ROWS;

    // ---- Layer 0: 16 rows x 256 nodes; thread tid == node tid for every row.
    float tb[16];
    #pragma unroll
    for (int i = 0; i < 16; ++i) tb[i] = t0[tid * 16 + i];

    const float4* __restrict__ x4 = (const float4*)x;  // row stride 256 float4s
    #pragma unroll
    for (int r = 0; r < ROWS; ++r) {
        float4 v = x4[(rowBase + r) * 256 + tid];      // fully coalesced 16B/lane
        s0[r * 256 + tid] = lut4(tb, v.x, v.y, v.z, v.w);
    }
    __syncthreads();

    // ---- Layer 1: 16 rows x 64 nodes = 1024 tasks, 4 per thread.
    {
        const int node = tid & 63;
        float tbl[16];
        #pragma unroll
        for (int i = 0; i < 16; ++i) tbl[i] = t1[node * 16 + i];
        #pragma unroll
        for (int k = 0; k < 4; ++k) {
            const int r = (tid >> 6) + 4 * k;
            float4 v = *(const float4*)&s0[r * 256 + node * 4];  // contiguous b128
            s1[r * 64 + node] = lut4(tbl, v.x, v.y, v.z, v.w);
        }
    }
    __syncthreads();

    // ---- Layer 2: 16 rows x 16 nodes = 256 tasks, 1 per thread.
    {
        const int r = tid >> 4, node = tid & 15;
        float tbl[16];
        #pragma unroll
        for (int i = 0; i < 16; ++i) tbl[i] = t2[node * 16 + i];
        float4 v = *(const float4*)&s1[r * 64 + node * 4];
        s2[r * 16 + node] = lut4(tbl, v.x, v.y, v.z, v.w);
    }
    __syncthreads();

    // ---- Layer 3: 16 rows x 4 nodes = 64 tasks.
    if (tid < 64) {
        const int r = tid >> 2, node = tid & 3;
        float tbl[16];
        #pragma unroll
        for (int i = 0; i < 16; ++i) tbl[i] = t3[node * 16 + i];
        float4 v = *(const float4*)&s2[r * 16 + node * 4];
        s3[r * 4 + node] = lut4(tbl, v.x, v.y, v.z, v.w);
    }
    __syncthreads();

    // ---- Layer 4: 16 rows x 1 node -> output.
    if (tid < 16) {
        float tbl[16];
        #pragma unroll
        for (int i = 0; i < 16; ++i) tbl[i] = t4[i];
        float4 v = *(const float4*)&s3[tid * 4];
        out[rowBase + tid] = lut4(tbl, v.x, v.y, v.z, v.w);
    }
}

extern "C" void kernel_launch(void* const* d_in, const int* in_sizes, int n_in,
                              void* d_out, int out_size, void* d_ws, size_t ws_size,
                              hipStream_t stream) {
    const float* x  = (const float*)d_in[0];
    const float* t0 = (const float*)d_in[1];
    const float* t1 = (const float*)d_in[2];
    const float* t2 = (const float*)d_in[3];
    const float* t3 = (const float*)d_in[4];
    const float* t4 = (const float*)d_in[5];
    float* out = (float*)d_out;

    const int B = in_sizes[0] / 1024;          // 32768
    const int grid = B / ROWS;                  // 2048 blocks
    lut_tree_kernel<<<grid, 256, 0, stream>>>(x, t0, t1, t2, t3, t4, out);
}

// Round 3
// 187.363 us; speedup vs baseline: 1.0531x; 1.0531x over previous
//
#include <hip/hip_runtime.h>

#define ROWS 8    // batch rows processed per block (LDS = 10.75 KB -> high occupancy)

typedef float floatx4 __attribute__((ext_vector_type(4)));

// 4-input multilinear LUT via iterated lerp with precomputed level-0 diffs:
// base[i] = t[2i], diff[i] = t[2i+1] - t[2i]  (row-invariant, amortized).
__device__ __forceinline__ float lut4_pre(const float* __restrict__ base,
                                          const float* __restrict__ diff,
                                          float x0, float x1, float x2, float x3) {
    float u0 = fmaf(x0, diff[0], base[0]);
    float u1 = fmaf(x0, diff[1], base[1]);
    float u2 = fmaf(x0, diff[2], base[2]);
    float u3 = fmaf(x0, diff[3], base[3]);
    float u4 = fmaf(x0, diff[4], base[4]);
    float u5 = fmaf(x0, diff[5], base[5]);
    float u6 = fmaf(x0, diff[6], base[6]);
    float u7 = fmaf(x0, diff[7], base[7]);
    float v0 = fmaf(x1, u1 - u0, u0);
    float v1 = fmaf(x1, u3 - u2, u2);
    float v2 = fmaf(x1, u5 - u4, u4);
    float v3 = fmaf(x1, u7 - u6, u6);
    float w0 = fmaf(x2, v1 - v0, v0);
    float w1 = fmaf(x2, v3 - v2, v2);
    return fmaf(x3, w1 - w0, w0);
}

__device__ __forceinline__ void load_tbl(const float* __restrict__ t, int node,
                                         float* __restrict__ base,
                                         float* __restrict__ diff) {
    #pragma unroll
    for (int i = 0; i < 8; ++i) {
        float a = t[node * 16 + 2 * i];
        float b = t[node * 16 + 2 * i + 1];
        base[i] = a;
        diff[i] = b - a;
    }
}

__global__ __launch_bounds__(256) void lut_tree_kernel(
    const float* __restrict__ x,
    const float* __restrict__ t0, const float* __restrict__ t1,
    const float* __restrict__ t2, const float* __restrict__ t3,
    const float* __restrict__ t4, float* __restrict__ out) {

    __shared__ float s0[ROWS * 256];
    __shared__ float s1[ROWS * 64];
    __shared__ float s2[ROWS * 16];
    __shared__ float s3[ROWS * 4];

    const int tid = threadIdx.x;
    const int rowBase = blockIdx.x * ROWS;

    // ---- Layer 0: ROWS rows x 256 nodes; thread tid == node tid for every row.
    float b0[8], d0[8];
    load_tbl(t0, tid, b0, d0);

    const floatx4* __restrict__ x4 = (const floatx4*)x;  // row stride 256 float4s
    #pragma unroll
    for (int r = 0; r < ROWS; ++r) {
        floatx4 v = __builtin_nontemporal_load(&x4[(rowBase + r) * 256 + tid]);
        s0[r * 256 + tid] = lut4_pre(b0, d0, v.x, v.y, v.z, v.w);
    }
    __syncthreads();

    // ---- Layer 1: ROWS x 64 nodes = 512 tasks, 2 per thread.
    {
        const int node = tid & 63;
        float b[8], d[8];
        load_tbl(t1, node, b, d);
        #pragma unroll
        for (int k = 0; k < 2; ++k) {
            const int r = (tid >> 6) + 4 * k;
            floatx4 v = *(const floatx4*)&s0[r * 256 + node * 4];  // contiguous b128
            s1[r * 64 + node] = lut4_pre(b, d, v.x, v.y, v.z, v.w);
        }
    }
    __syncthreads();

    // ---- Layer 2: ROWS x 16 nodes = 128 tasks.
    if (tid < ROWS * 16) {
        const int r = tid >> 4, node = tid & 15;
        float b[8], d[8];
        load_tbl(t2, node, b, d);
        floatx4 v = *(const floatx4*)&s1[r * 64 + node * 4];
        s2[r * 16 + node] = lut4_pre(b, d, v.x, v.y, v.z, v.w);
    }
    __syncthreads();

    // ---- Layer 3: ROWS x 4 nodes = 32 tasks.
    if (tid < ROWS * 4) {
        const int r = tid >> 2, node = tid & 3;
        float b[8], d[8];
        load_tbl(t3, node, b, d);
        floatx4 v = *(const floatx4*)&s2[r * 16 + node * 4];
        s3[r * 4 + node] = lut4_pre(b, d, v.x, v.y, v.z, v.w);
    }
    __syncthreads();

    // ---- Layer 4: ROWS x 1 node -> output.
    if (tid < ROWS) {
        float b[8], d[8];
        load_tbl(t4, 0, b, d);
        floatx4 v = *(const floatx4*)&s3[tid * 4];
        out[rowBase + tid] = lut4_pre(b, d, v.x, v.y, v.z, v.w);
    }
}

extern "C" void kernel_launch(void* const* d_in, const int* in_sizes, int n_in,
                              void* d_out, int out_size, void* d_ws, size_t ws_size,
                              hipStream_t stream) {
    const float* x  = (const float*)d_in[0];
    const float* t0 = (const float*)d_in[1];
    const float* t1 = (const float*)d_in[2];
    const float* t2 = (const float*)d_in[3];
    const float* t3 = (const float*)d_in[4];
    const float* t4 = (const float*)d_in[5];
    float* out = (float*)d_out;

    const int B = in_sizes[0] / 1024;          // 32768
    const int grid = B / ROWS;                  // 4096 blocks
    lut_tree_kernel<<<grid, 256, 0, stream>>>(x, t0, t1, t2, t3, t4, out);
}

// Round 4
// 186.505 us; speedup vs baseline: 1.0579x; 1.0046x over previous
//
#include <hip/hip_runtime.h>

#define ROWS 8    // batch rows processed per block (LDS = 10.75 KB -> high occupancy)

typedef float floatx4 __attribute__((ext_vector_type(4)));

// 4-input multilinear LUT via iterated lerp with precomputed level-0 diffs:
// base[i] = t[2i], diff[i] = t[2i+1] - t[2i]  (row-invariant, amortized).
__device__ __forceinline__ float lut4_pre(const float* __restrict__ base,
                                          const float* __restrict__ diff,
                                          float x0, float x1, float x2, float x3) {
    float u0 = fmaf(x0, diff[0], base[0]);
    float u1 = fmaf(x0, diff[1], base[1]);
    float u2 = fmaf(x0, diff[2], base[2]);
    float u3 = fmaf(x0, diff[3], base[3]);
    float u4 = fmaf(x0, diff[4], base[4]);
    float u5 = fmaf(x0, diff[5], base[5]);
    float u6 = fmaf(x0, diff[6], base[6]);
    float u7 = fmaf(x0, diff[7], base[7]);
    float v0 = fmaf(x1, u1 - u0, u0);
    float v1 = fmaf(x1, u3 - u2, u2);
    float v2 = fmaf(x1, u5 - u4, u4);
    float v3 = fmaf(x1, u7 - u6, u6);
    float w0 = fmaf(x2, v1 - v0, v0);
    float w1 = fmaf(x2, v3 - v2, v2);
    return fmaf(x3, w1 - w0, w0);
}

__device__ __forceinline__ void load_tbl(const float* __restrict__ t, int node,
                                         float* __restrict__ base,
                                         float* __restrict__ diff) {
    #pragma unroll
    for (int i = 0; i < 8; ++i) {
        float a = t[node * 16 + 2 * i];
        float b = t[node * 16 + 2 * i + 1];
        base[i] = a;
        diff[i] = b - a;
    }
}

__global__ __launch_bounds__(256) void lut_tree_kernel(
    const float* __restrict__ x,
    const float* __restrict__ t0, const float* __restrict__ t1,
    const float* __restrict__ t2, const float* __restrict__ t3,
    const float* __restrict__ t4, float* __restrict__ out) {

    __shared__ float s0[ROWS * 256];
    __shared__ float s1[ROWS * 64];
    __shared__ float s2[ROWS * 16];
    __shared__ float s3[ROWS * 4];

    const int tid = threadIdx.x;
    const int rowBase = blockIdx.x * ROWS;

    const floatx4* __restrict__ x4 = (const floatx4*)x;  // row stride 256 float4s

    // ---- Layer 0: issue ALL global loads first (8 outstanding 16B/lane -> max MLP),
    // then compute. Thread tid == node tid for every row.
    floatx4 v[ROWS];
    #pragma unroll
    for (int r = 0; r < ROWS; ++r)
        v[r] = __builtin_nontemporal_load(&x4[(rowBase + r) * 256 + tid]);

    float b0[8], d0[8];
    load_tbl(t0, tid, b0, d0);

    #pragma unroll
    for (int r = 0; r < ROWS; ++r)
        s0[r * 256 + tid] = lut4_pre(b0, d0, v[r].x, v[r].y, v[r].z, v[r].w);
    __syncthreads();

    // ---- Layer 1: ROWS x 64 nodes = 512 tasks, 2 per thread.
    {
        const int node = tid & 63;
        float b[8], d[8];
        load_tbl(t1, node, b, d);
        #pragma unroll
        for (int k = 0; k < 2; ++k) {
            const int r = (tid >> 6) + 4 * k;
            floatx4 w = *(const floatx4*)&s0[r * 256 + node * 4];  // contiguous b128
            s1[r * 64 + node] = lut4_pre(b, d, w.x, w.y, w.z, w.w);
        }
    }
    __syncthreads();

    // ---- Layer 2: ROWS x 16 nodes = 128 tasks.
    if (tid < ROWS * 16) {
        const int r = tid >> 4, node = tid & 15;
        float b[8], d[8];
        load_tbl(t2, node, b, d);
        floatx4 w = *(const floatx4*)&s1[r * 64 + node * 4];
        s2[r * 16 + node] = lut4_pre(b, d, w.x, w.y, w.z, w.w);
    }
    __syncthreads();

    // ---- Layer 3: ROWS x 4 nodes = 32 tasks.
    if (tid < ROWS * 4) {
        const int r = tid >> 2, node = tid & 3;
        float b[8], d[8];
        load_tbl(t3, node, b, d);
        floatx4 w = *(const floatx4*)&s2[r * 16 + node * 4];
        s3[r * 4 + node] = lut4_pre(b, d, w.x, w.y, w.z, w.w);
    }
    __syncthreads();

    // ---- Layer 4: ROWS x 1 node -> output.
    if (tid < ROWS) {
        float b[8], d[8];
        load_tbl(t4, 0, b, d);
        floatx4 w = *(const floatx4*)&s3[tid * 4];
        out[rowBase + tid] = lut4_pre(b, d, w.x, w.y, w.z, w.w);
    }
}

extern "C" void kernel_launch(void* const* d_in, const int* in_sizes, int n_in,
                              void* d_out, int out_size, void* d_ws, size_t ws_size,
                              hipStream_t stream) {
    const float* x  = (const float*)d_in[0];
    const float* t0 = (const float*)d_in[1];
    const float* t1 = (const float*)d_in[2];
    const float* t2 = (const float*)d_in[3];
    const float* t3 = (const float*)d_in[4];
    const float* t4 = (const float*)d_in[5];
    float* out = (float*)d_out;

    const int B = in_sizes[0] / 1024;          // 32768
    const int grid = B / ROWS;                  // 4096 blocks
    lut_tree_kernel<<<grid, 256, 0, stream>>>(x, t0, t1, t2, t3, t4, out);
}